// Round 7
// baseline (710.458 us; speedup 1.0000x reference)
//
#include <hip/hip_runtime.h>

#define TPB 256
typedef unsigned short u16;
typedef __attribute__((ext_vector_type(8))) short short8v;
typedef __attribute__((ext_vector_type(4))) float f32x4;

__device__ __forceinline__ u16 f2bf(float x) {
    unsigned u = __float_as_uint(x);
    return (u16)((u + 0x7FFFu + ((u >> 16) & 1u)) >> 16);
}
__device__ __forceinline__ float bf2f(u16 h) {
    return __uint_as_float(((unsigned)h) << 16);
}

// LDS 16B-chunk XOR swizzle (CS = chunks per row = CI/8).
template<int CS>
__device__ __forceinline__ int swzc(int r, int c) {
    constexpr int PH = (CS == 8) ? 0 : 1;   // CS==8: 128B rows, CS==4: 64B rows
    return c ^ ((r >> PH) & (CS - 1));
}

// bijective XCD-contiguity swizzle (m204): round-robin hw dispatch -> each
// XCD owns a contiguous chunk of block rows (L2 gather locality).
__device__ __forceinline__ int xcd_swz(int bid, int nwg) {
    int q = nwg >> 3, r = nwg & 7;
    int x = bid & 7, idx = bid >> 3;
    return (x < r ? x * (q + 1) : r * (q + 1) + (x - r) * q) + idx;
}

// ---- mean-VFE
__global__ void vfe_kernel(const float* __restrict__ voxels,
                           const int* __restrict__ nump,
                           float* __restrict__ x, int N) {
    int i = blockIdx.x * blockDim.x + threadIdx.x;
    if (i >= N * 4) return;
    int n = i >> 2, c = i & 3;
    const float* v = voxels + (long)n * 20 + c;
    float s = v[0] + v[4] + v[8] + v[12] + v[16];
    x[i] = s / fmaxf((float)nump[n], 1.0f);
}

// ---- invert rulebook: inv[out_row][k] = in_row (or -1)
__global__ void inv_build_kernel(const int* __restrict__ rb_in,
                                 const int* __restrict__ rb_out,
                                 int* __restrict__ inv,
                                 int KP, int P, int K, int n_in) {
    int t = blockIdx.x * blockDim.x + threadIdx.x;
    if (t >= KP) return;
    int ii = rb_in[t];
    if (ii == n_in) return;
    int k = t / P;
    inv[(long)rb_out[t] * K + k] = ii;
}

// ---- weight prep: fp32 [K][ci][co] -> bf16 hi/lo planes laid out [K][co][ci]
struct WPE { const float* w; u16* oh; u16* ol; int K, ci, co, total; };
struct WPA { WPE e[9]; };
__global__ void wprep_kernel(WPA a, int grand) {
    int t = blockIdx.x * blockDim.x + threadIdx.x;
    if (t >= grand) return;
    #pragma unroll
    for (int i = 0; i < 9; ++i) {
        if (t < a.e[i].total) {
            const WPE& E = a.e[i];
            int cc = E.ci * E.co;
            int k = t / cc, r = t % cc, c = r / E.co, o = r % E.co;
            float x = E.w[t];
            u16 h = f2bf(x);
            float lf = x - bf2f(h);
            long d = ((long)k * E.co + o) * E.ci + c;
            E.oh[d] = h; E.ol[d] = f2bf(lf);
            return;
        }
        t -= a.e[i].total;
    }
}

// ---- direct tiny-CI conv (layer 0): thread = (row, 4-col group). W in LDS.
template<int CO, int K>
__global__ __launch_bounds__(256)
void dconv4_kernel(const float* __restrict__ feats,   // [n][4]
                   const float* __restrict__ w,       // [K][4][CO]
                   const float* __restrict__ bn,
                   const int* __restrict__ inv,       // [n_out][K]
                   float* __restrict__ out, int n_out) {
    constexpr int OG = CO / 4;
    __shared__ float sW[K * 4 * CO];
    for (int i = threadIdx.x; i < K * 4 * CO; i += 256) sW[i] = w[i];
    __syncthreads();
    long t = (long)blockIdx.x * 256 + threadIdx.x;
    int row = (int)(t / OG), og = (int)(t % OG);
    if (row >= n_out) return;
    float a0 = 0.f, a1 = 0.f, a2 = 0.f, a3 = 0.f;
    for (int k = 0; k < K; ++k) {
        int idx = inv[(long)row * K + k];
        if (idx < 0) continue;
        float4 av = *(const float4*)(feats + (long)idx * 4);
        const float* wk = sW + k * 4 * CO + og * 4;
        #pragma unroll
        for (int ci = 0; ci < 4; ++ci) {
            float a = (&av.x)[ci];
            a0 = fmaf(a, wk[ci * CO + 0], a0);
            a1 = fmaf(a, wk[ci * CO + 1], a1);
            a2 = fmaf(a, wk[ci * CO + 2], a2);
            a3 = fmaf(a, wk[ci * CO + 3], a3);
        }
    }
    float4 g = *(const float4*)(bn + og * 4);
    float4 b = *(const float4*)(bn + CO + og * 4);
    float4 m = *(const float4*)(bn + 2 * CO + og * 4);
    float4 v = *(const float4*)(bn + 3 * CO + og * 4);
    float4 o;
    o.x = fmaxf((a0 - m.x) * rsqrtf(v.x + 1e-3f) * g.x + b.x, 0.f);
    o.y = fmaxf((a1 - m.y) * rsqrtf(v.y + 1e-3f) * g.y + b.y, 0.f);
    o.z = fmaxf((a2 - m.z) * rsqrtf(v.z + 1e-3f) * g.z + b.z, 0.f);
    o.w = fmaxf((a3 - m.w) * rsqrtf(v.w + 1e-3f) * g.w + b.w, 0.f);
    *(float4*)(out + (long)row * CO + og * 4) = o;
}

// ---- fp32 pipelined conv (layers 1-2), fused BN+ReLU; optional bf16-plane emit
template<int CI, int CO, int TP, int K, bool EMIT16>
__global__ __launch_bounds__(256, 4)
void conv_kernel(const float* __restrict__ feats,
                 const float* __restrict__ w,    // [K][CI][CO]
                 const float* __restrict__ bn,
                 const int* __restrict__ inv,    // [n_out][K]
                 float* __restrict__ out,
                 u16* __restrict__ oh, u16* __restrict__ ol,
                 int n_out) {
    constexpr int OG  = CO / 4;
    constexpr int PTH = 256 / OG;
    constexpr int PT  = TP / PTH;
    constexpr int CIP = CI + 4;
    constexpr int W4  = CI * CO / 4;
    constexpr int WCH = (W4 + 255) / 256;
    constexpr int TR  = CI / 4;
    constexpr int RPS = 256 / TR;
    constexpr int ASW = (TP + RPS - 1) / RPS;

    __shared__ float sW[2][CI * CO];
    __shared__ float sA[2][TP * CIP];
    __shared__ int   sI[TP * K];

    const int brow = blockIdx.x * TP;
    const int t  = threadIdx.x;
    const int og = t % OG;
    const int pg = t / OG;

    {
        long base = (long)brow * K, lim = (long)n_out * K;
        for (int i = t; i < TP * K; i += 256)
            sI[i] = (base + i < lim) ? inv[base + i] : -1;
    }

    float4 wreg[WCH];
    float4 areg[ASW];

    auto load_regs = [&](int k) {
        const float4* src = (const float4*)(w + (long)k * CI * CO);
        #pragma unroll
        for (int c = 0; c < WCH; ++c) {
            int i = c * 256 + t;
            if (W4 >= 256 || i < W4) wreg[c] = src[i];
        }
        #pragma unroll
        for (int s = 0; s < ASW; ++s) {
            int r = s * RPS + t / TR;
            int c = (t % TR) * 4;
            float4 v = make_float4(0.f, 0.f, 0.f, 0.f);
            if (r < TP) {
                int idx = sI[r * K + k];
                if (idx >= 0) v = *(const float4*)(feats + (long)idx * CI + c);
            }
            areg[s] = v;
        }
    };
    auto store_lds = [&](int b) {
        #pragma unroll
        for (int c = 0; c < WCH; ++c) {
            int i = c * 256 + t;
            if (W4 >= 256 || i < W4) ((float4*)sW[b])[i] = wreg[c];
        }
        #pragma unroll
        for (int s = 0; s < ASW; ++s) {
            int r = s * RPS + t / TR;
            int c = (t % TR) * 4;
            if (r < TP) *(float4*)(&sA[b][r * CIP + c]) = areg[s];
        }
    };

    float acc[PT][4];
    #pragma unroll
    for (int i = 0; i < PT; ++i)
        acc[i][0] = acc[i][1] = acc[i][2] = acc[i][3] = 0.f;

    auto compute = [&](int b) {
        #pragma unroll 4
        for (int kk = 0; kk < CI; ++kk) {
            float4 wv = *(const float4*)(&sW[b][kk * CO + og * 4]);
            #pragma unroll
            for (int i = 0; i < PT; ++i) {
                float a = sA[b][(pg * PT + i) * CIP + kk];
                acc[i][0] = fmaf(a, wv.x, acc[i][0]);
                acc[i][1] = fmaf(a, wv.y, acc[i][1]);
                acc[i][2] = fmaf(a, wv.z, acc[i][2]);
                acc[i][3] = fmaf(a, wv.w, acc[i][3]);
            }
        }
    };

    __syncthreads();
    int cur = 0;
    load_regs(0);
    store_lds(0);
    for (int k = 0; k < K; ++k) {
        __syncthreads();
        if (k + 1 < K) load_regs(k + 1);
        compute(cur);
        if (k + 1 < K) store_lds(cur ^ 1);
        cur ^= 1;
    }

    float4 g = *(const float4*)(bn + og * 4);
    float4 b = *(const float4*)(bn + CO + og * 4);
    float4 m = *(const float4*)(bn + 2 * CO + og * 4);
    float4 v = *(const float4*)(bn + 3 * CO + og * 4);
    float s0 = rsqrtf(v.x + 1e-3f) * g.x;
    float s1 = rsqrtf(v.y + 1e-3f) * g.y;
    float s2 = rsqrtf(v.z + 1e-3f) * g.z;
    float s3 = rsqrtf(v.w + 1e-3f) * g.w;
    #pragma unroll
    for (int i = 0; i < PT; ++i) {
        int grow = brow + pg * PT + i;
        if (grow < n_out) {
            float o4[4];
            o4[0] = fmaxf(fmaf(acc[i][0] - m.x, s0, b.x), 0.f);
            o4[1] = fmaxf(fmaf(acc[i][1] - m.y, s1, b.y), 0.f);
            o4[2] = fmaxf(fmaf(acc[i][2] - m.z, s2, b.z), 0.f);
            o4[3] = fmaxf(fmaf(acc[i][3] - m.w, s3, b.w), 0.f);
            if (EMIT16) {
                long base = (long)grow * CO + og * 4;
                #pragma unroll
                for (int c = 0; c < 4; ++c) {
                    u16 h = f2bf(o4[c]);
                    oh[base + c] = h;
                    ol[base + c] = f2bf(o4[c] - bf2f(h));
                }
            } else {
                *(float4*)(out + (long)grow * CO + og * 4) =
                    make_float4(o4[0], o4[1], o4[2], o4[3]);
            }
        }
    }
}

// ---- MFMA sparse conv: 64-row block (XCD-swizzled), 2x2 wave grid, bf16
// hi/lo 3-term split, XOR-swizzled single LDS buffer, early-issue register
// prefetch. MINW = min waves/EU (VGPR budget: 512/MINW) -- keeps the
// staging arrays in registers (round-6 spill: VGPR capped at 52 -> 246 MB
// scratch writes). fp32 partials to slab blockIdx.y; no atomics.
template<int CI, int CO, int K, int MINW>
__global__ __launch_bounds__(256, MINW)
void mconv_kernel(const u16* __restrict__ fh, const u16* __restrict__ fl,
                  const u16* __restrict__ wh, const u16* __restrict__ wl,
                  const int* __restrict__ inv,
                  float* __restrict__ part, long slab_elems,
                  int n_out, int kpb) {
    constexpr int CS  = CI / 8;
    constexpr int KS  = CI / 32;
    constexpr int NTW = CO / 32;
    constexpr int ACH = 64 * CS;
    constexpr int BCH = CO * CS;
    constexpr int AR  = (ACH + 255) / 256;
    constexpr int BR  = (BCH + 255) / 256;

    __shared__ __align__(16) u16 sAh[64 * CI];
    __shared__ __align__(16) u16 sAl[64 * CI];
    __shared__ __align__(16) u16 sBh[CO * CI];
    __shared__ __align__(16) u16 sBl[CO * CI];

    const int t = threadIdx.x;
    const int bx = xcd_swz(blockIdx.x, gridDim.x);
    const int brow = bx * 64;
    const int kbeg = blockIdx.y * kpb;
    const int kend = (kbeg + kpb < K) ? (kbeg + kpb) : K;

    const int lane = t & 63, wid = t >> 6;
    const int wr = wid >> 1, wc = wid & 1;
    const int frow = lane & 15;
    const int fch  = lane >> 4;

    f32x4 acc[2][NTW];
    #pragma unroll
    for (int mt = 0; mt < 2; ++mt)
        #pragma unroll
        for (int nt = 0; nt < NTW; ++nt) {
            acc[mt][nt][0] = 0.f; acc[mt][nt][1] = 0.f;
            acc[mt][nt][2] = 0.f; acc[mt][nt][3] = 0.f;
        }

    float4 aregH[AR], aregL[AR], bregH[BR], bregL[BR];

    auto load_regs = [&](int k) {
        #pragma unroll
        for (int j = 0; j < AR; ++j) {
            int i = j * 256 + t;
            if (ACH % 256 == 0 || i < ACH) {
                int r = i / CS, c = i % CS;
                int grow = brow + r;
                int idx = (grow < n_out) ? inv[(long)grow * K + k] : -1;
                float4 h = make_float4(0.f, 0.f, 0.f, 0.f), l = h;
                if (idx >= 0) {
                    h = *(const float4*)(fh + (long)idx * CI + c * 8);
                    l = *(const float4*)(fl + (long)idx * CI + c * 8);
                }
                aregH[j] = h; aregL[j] = l;
            }
        }
        const float4* sh = (const float4*)(wh + (long)k * CO * CI);
        const float4* sl = (const float4*)(wl + (long)k * CO * CI);
        #pragma unroll
        for (int j = 0; j < BR; ++j) {
            int i = j * 256 + t;
            if (BCH % 256 == 0 || i < BCH) { bregH[j] = sh[i]; bregL[j] = sl[i]; }
        }
    };
    auto store_lds = [&]() {
        #pragma unroll
        for (int j = 0; j < AR; ++j) {
            int i = j * 256 + t;
            if (ACH % 256 == 0 || i < ACH) {
                int r = i / CS, c = i % CS;
                int o = r * CI + swzc<CS>(r, c) * 8;
                *(float4*)(sAh + o) = aregH[j];
                *(float4*)(sAl + o) = aregL[j];
            }
        }
        #pragma unroll
        for (int j = 0; j < BR; ++j) {
            int i = j * 256 + t;
            if (BCH % 256 == 0 || i < BCH) {
                int r = i / CS, c = i % CS;
                int o = r * CI + swzc<CS>(r, c) * 8;
                *(float4*)(sBh + o) = bregH[j];
                *(float4*)(sBl + o) = bregL[j];
            }
        }
    };
    auto compute = [&]() {
        #pragma unroll
        for (int ks = 0; ks < KS; ++ks) {
            int c = ks * 4 + fch;
            short8v ah[2], al[2];
            #pragma unroll
            for (int mt = 0; mt < 2; ++mt) {
                int r = wr * 32 + mt * 16 + frow;
                int o = r * CI + swzc<CS>(r, c) * 8;
                ah[mt] = *(const short8v*)(sAh + o);
                al[mt] = *(const short8v*)(sAl + o);
            }
            #pragma unroll
            for (int nt = 0; nt < NTW; ++nt) {
                int col = wc * (CO / 2) + nt * 16 + frow;
                int o = col * CI + swzc<CS>(col, c) * 8;
                short8v bh = *(const short8v*)(sBh + o);
                short8v bl = *(const short8v*)(sBl + o);
                #pragma unroll
                for (int mt = 0; mt < 2; ++mt) {
                    acc[mt][nt] = __builtin_amdgcn_mfma_f32_16x16x32_bf16(ah[mt], bh, acc[mt][nt], 0, 0, 0);
                    acc[mt][nt] = __builtin_amdgcn_mfma_f32_16x16x32_bf16(ah[mt], bl, acc[mt][nt], 0, 0, 0);
                    acc[mt][nt] = __builtin_amdgcn_mfma_f32_16x16x32_bf16(al[mt], bh, acc[mt][nt], 0, 0, 0);
                }
            }
        }
    };

    load_regs(kbeg);
    for (int k = kbeg; k < kend; ++k) {
        __syncthreads();                 // prior compute done reading LDS
        store_lds();
        __syncthreads();                 // LDS staged
        if (k + 1 < kend) load_regs(k + 1);   // loads in flight under MFMA
        compute();
    }

    float* dst = part + (long)blockIdx.y * slab_elems;
    #pragma unroll
    for (int mt = 0; mt < 2; ++mt) {
        int orow0 = brow + wr * 32 + mt * 16 + (lane >> 4) * 4;
        #pragma unroll
        for (int nt = 0; nt < NTW; ++nt) {
            int ocol = wc * (CO / 2) + nt * 16 + (lane & 15);
            #pragma unroll
            for (int j = 0; j < 4; ++j) {
                int r = orow0 + j;
                if (r < n_out) dst[(long)r * CO + ocol] = acc[mt][nt][j];
            }
        }
    }
}

// ---- slab reduce + BN + ReLU (+ bf16 hi/lo emit OR fp32 out)
template<bool EMIT16>
__global__ void reduce_bnrelu_kernel(const float* __restrict__ part, long stride,
                                     int ys, const float* __restrict__ bn, int co,
                                     float* __restrict__ outf,
                                     u16* __restrict__ oh, u16* __restrict__ ol,
                                     long total) {
    long t = (long)blockIdx.x * blockDim.x + threadIdx.x;
    if (t >= total) return;
    float s = 0.f;
    for (int y = 0; y < ys; ++y) s += part[(long)y * stride + t];
    int o = (int)(t % co);
    float g = bn[o], b = bn[co + o], m = bn[2 * co + o], v = bn[3 * co + o];
    float yv = fmaxf((s - m) * rsqrtf(v + 1e-3f) * g + b, 0.f);
    if (EMIT16) {
        u16 h = f2bf(yv);
        oh[t] = h;
        ol[t] = f2bf(yv - bf2f(h));
    } else {
        outf[t] = yv;
    }
}

// ---- per-batch max pool: LDS accumulation, few global atomics
__global__ void segmax_kernel(const float* __restrict__ x,
                              const int* __restrict__ bidx,
                              float* __restrict__ out, int rows, int nb) {
    __shared__ float sM[8 * 128];
    for (int i = threadIdx.x; i < nb * 128; i += 256) sM[i] = 0.f;
    __syncthreads();
    int c = threadIdx.x & 127;
    int sub = threadIdx.x >> 7;
    for (int r = blockIdx.x * 2 + sub; r < rows; r += gridDim.x * 2) {
        float v = x[(long)r * 128 + c];
        int b = bidx[r];
        atomicMax((int*)&sM[b * 128 + c], __float_as_int(v));
    }
    __syncthreads();
    for (int i = threadIdx.x; i < nb * 128; i += 256)
        atomicMax((int*)out + i, __float_as_int(sM[i]));
}

extern "C" void kernel_launch(void* const* d_in, const int* in_sizes, int n_in,
                              void* d_out, int out_size, void* d_ws, size_t ws_size,
                              hipStream_t stream) {
    (void)n_in;
    const float* voxels = (const float*)d_in[24];
    const int*   nump   = (const int*)d_in[25];
    const int N  = in_sizes[25];
    const int n2 = in_sizes[30] / 27;
    const int n3 = in_sizes[34] / 27;
    const int n4 = in_sizes[38] / 27;
    const int n5 = in_sizes[42];

    struct L { int wi, rb, K, ci, co, nin, nout; };
    const L layers[12] = {
        {0,  26, 27,  4,  16, N,  N }, {1,  26, 27, 16,  16, N,  N },
        {2,  28, 27, 16,  32, N,  n2}, {3,  30, 27, 32,  32, n2, n2},
        {4,  30, 27, 32,  32, n2, n2}, {5,  32, 27, 32,  64, n2, n3},
        {6,  34, 27, 64,  64, n3, n3}, {7,  34, 27, 64,  64, n3, n3},
        {8,  36, 27, 64,  64, n3, n4}, {9,  38, 27, 64,  64, n4, n4},
        {10, 38, 27, 64,  64, n4, n4}, {11, 40,  3, 64, 128, n4, n5},
    };

    // ---- workspace carve-up (fixed part), remainder = split-K slab budget
    size_t inv_elems = 0, feat_elems = (size_t)N * 4, wt_elems = 0;
    for (int i = 0; i < 12; ++i) {
        size_t ie = (size_t)layers[i].nout * layers[i].K;
        size_t fe = (size_t)layers[i].nout * layers[i].co;
        if (ie > inv_elems)  inv_elems  = ie;
        if (fe > feat_elems) feat_elems = fe;
        if (i >= 3) wt_elems += (size_t)layers[i].K * layers[i].ci * layers[i].co;
    }
    auto al = [](size_t x) { return (x + 255) & ~(size_t)255; };
    char* p = (char*)d_ws;
    int*   inv  = (int*)p;   p += al(inv_elems * 4);
    float* bufA = (float*)p; p += al(feat_elems * 4);
    float* bufB = (float*)p; p += al(feat_elems * 4);
    u16* ph[2]; u16* pl[2];
    ph[0] = (u16*)p; p += al(feat_elems * 2);
    pl[0] = (u16*)p; p += al(feat_elems * 2);
    ph[1] = (u16*)p; p += al(feat_elems * 2);
    pl[1] = (u16*)p; p += al(feat_elems * 2);
    u16* wth = (u16*)p; p += al(wt_elems * 2);
    u16* wtl = (u16*)p; p += al(wt_elems * 2);
    float* slab = (float*)p;
    size_t slab_budget = ws_size - (size_t)((char*)slab - (char*)d_ws);

    // ---- VFE
    {
        long tot = (long)N * 4;
        vfe_kernel<<<dim3((unsigned)((tot + TPB - 1) / TPB)), dim3(TPB), 0, stream>>>(
            voxels, nump, bufA, N);
    }

    // ---- weight prep for MFMA layers
    size_t woff[9];
    {
        WPA wa;
        size_t off = 0;
        for (int i = 0; i < 9; ++i) {
            const L& l = layers[i + 3];
            woff[i] = off;
            wa.e[i].w  = (const float*)d_in[2 * l.wi];
            wa.e[i].oh = wth + off;
            wa.e[i].ol = wtl + off;
            wa.e[i].K = l.K; wa.e[i].ci = l.ci; wa.e[i].co = l.co;
            wa.e[i].total = l.K * l.ci * l.co;
            off += (size_t)wa.e[i].total;
        }
        int grand = (int)off;
        wprep_kernel<<<dim3((grand + TPB - 1) / TPB), dim3(TPB), 0, stream>>>(wa, grand);
    }

    int prev_rb = -1;
    auto build_inv = [&](const L& l) {
        if (l.rb == prev_rb) return;
        const int* rin  = (const int*)d_in[l.rb];
        const int* rout = (const int*)d_in[l.rb + 1];
        int P  = in_sizes[l.rb] / l.K;
        int KP = l.K * P;
        hipMemsetAsync(inv, 0xFF, (size_t)l.nout * l.K * sizeof(int), stream);
        inv_build_kernel<<<dim3((KP + TPB - 1) / TPB), dim3(TPB), 0, stream>>>(
            rin, rout, inv, KP, P, l.K, l.nin);
        prev_rb = l.rb;
    };

    // ---- layer 0: direct tiny-CI kernel
    {
        const L& l = layers[0];
        build_inv(l);
        long tot = (long)l.nout * 4;   // rows * (CO/4)
        dconv4_kernel<16, 27><<<dim3((unsigned)((tot + 255) / 256)), 256, 0, stream>>>(
            bufA, (const float*)d_in[0], (const float*)d_in[1], inv, bufB, l.nout);
    }
    // ---- layers 1-2: fp32 pipelined template
    {
        const L& l = layers[1];
        build_inv(l);
        conv_kernel<16, 16, 64, 27, false><<<dim3((l.nout + 63) / 64), 256, 0, stream>>>(
            bufB, (const float*)d_in[2], (const float*)d_in[3], inv,
            bufA, nullptr, nullptr, l.nout);
    }
    {
        const L& l = layers[2];
        build_inv(l);
        conv_kernel<16, 32, 64, 27, true><<<dim3((l.nout + 63) / 64), 256, 0, stream>>>(
            bufA, (const float*)d_in[4], (const float*)d_in[5], inv,
            nullptr, ph[0], pl[0], l.nout);
    }

    // ---- MFMA layers 3-11 (split-K sized to fill the chip, slab-budgeted)
    int cset = 0;
    for (int i = 3; i < 12; ++i) {
        const L& l = layers[i];
        build_inv(l);
        unsigned blocks = (unsigned)((l.nout + 63) / 64);
        int ys = 1;
        int ys_max = (l.K == 27) ? 27 : 3;
        while (ys < ys_max && blocks * (unsigned)ys < 768) ys *= 3;
        size_t per = (size_t)l.nout * l.co * 4;
        while (ys > 1 && (size_t)ys * per > slab_budget) ys /= 3;
        int kpb = (l.K + ys - 1) / ys;
        long slab_elems = (long)l.nout * l.co;
        dim3 grid(blocks, (unsigned)ys);
        const u16* fh = ph[cset];
        const u16* fl = pl[cset];
        const u16* whp = wth + woff[i - 3];
        const u16* wlp = wtl + woff[i - 3];

        switch (i) {
        case 3: case 4:
            mconv_kernel<32, 32, 27, 4><<<grid, 256, 0, stream>>>(
                fh, fl, whp, wlp, inv, slab, slab_elems, l.nout, kpb); break;
        case 5:
            mconv_kernel<32, 64, 27, 4><<<grid, 256, 0, stream>>>(
                fh, fl, whp, wlp, inv, slab, slab_elems, l.nout, kpb); break;
        case 11:
            mconv_kernel<64, 128, 3, 2><<<grid, 256, 0, stream>>>(
                fh, fl, whp, wlp, inv, slab, slab_elems, l.nout, kpb); break;
        default:
            mconv_kernel<64, 64, 27, 4><<<grid, 256, 0, stream>>>(
                fh, fl, whp, wlp, inv, slab, slab_elems, l.nout, kpb); break;
        }

        long total = (long)l.nout * l.co;
        unsigned rblocks = (unsigned)((total + TPB - 1) / TPB);
        const float* bn = (const float*)d_in[2 * l.wi + 1];
        if (i < 11) {
            reduce_bnrelu_kernel<true><<<dim3(rblocks), dim3(TPB), 0, stream>>>(
                slab, slab_elems, ys, bn, l.co,
                nullptr, ph[cset ^ 1], pl[cset ^ 1], total);
            cset ^= 1;
        } else {
            reduce_bnrelu_kernel<false><<<dim3(rblocks), dim3(TPB), 0, stream>>>(
                slab, slab_elems, ys, bn, l.co, bufA, nullptr, nullptr, total);
        }
    }

    // ---- segment max
    hipMemsetAsync(d_out, 0, (size_t)out_size * sizeof(float), stream);
    const int* bidx = (const int*)d_in[42];
    int nb = out_size / 128;
    segmax_kernel<<<dim3(128), dim3(256), 0, stream>>>(bufA, bidx, (float*)d_out, n5, nb);
}

// Round 9
// 505.102 us; speedup vs baseline: 1.4066x; 1.4066x over previous
//
#include <hip/hip_runtime.h>

#define TPB 256
typedef unsigned short u16;
typedef __attribute__((ext_vector_type(8))) short short8v;
typedef __attribute__((ext_vector_type(4))) float f32x4;

__device__ __forceinline__ u16 f2bf(float x) {
    unsigned u = __float_as_uint(x);
    return (u16)((u + 0x7FFFu + ((u >> 16) & 1u)) >> 16);
}
__device__ __forceinline__ float bf2f(u16 h) {
    return __uint_as_float(((unsigned)h) << 16);
}

// LDS 16B-chunk XOR swizzle (CS = chunks per row = CI/8).
template<int CS>
__device__ __forceinline__ int swzc(int r, int c) {
    constexpr int PH = (CS == 8) ? 0 : 1;   // CS==8: 128B rows, CS==4: 64B rows
    return c ^ ((r >> PH) & (CS - 1));
}

// bijective XCD-contiguity swizzle (m204)
__device__ __forceinline__ int xcd_swz(int bid, int nwg) {
    int q = nwg >> 3, r = nwg & 7;
    int x = bid & 7, idx = bid >> 3;
    return (x < r ? x * (q + 1) : r * (q + 1) + (x - r) * q) + idx;
}

// async global->LDS, 16B per lane; LDS dest = wave-uniform base + lane*16
__device__ __forceinline__ void gld16(const u16* g, u16* l) {
    __builtin_amdgcn_global_load_lds(
        (const __attribute__((address_space(1))) void*)g,
        (__attribute__((address_space(3))) void*)l, 16, 0, 0);
}

// ---- mean-VFE
__global__ void vfe_kernel(const float* __restrict__ voxels,
                           const int* __restrict__ nump,
                           float* __restrict__ x, int N) {
    int i = blockIdx.x * blockDim.x + threadIdx.x;
    if (i >= N * 4) return;
    int n = i >> 2, c = i & 3;
    const float* v = voxels + (long)n * 20 + c;
    float s = v[0] + v[4] + v[8] + v[12] + v[16];
    x[i] = s / fmaxf((float)nump[n], 1.0f);
}

// ---- invert rulebook: inv[out_row][k] = in_row (or -1)
__global__ void inv_build_kernel(const int* __restrict__ rb_in,
                                 const int* __restrict__ rb_out,
                                 int* __restrict__ inv,
                                 int KP, int P, int K, int n_in) {
    int t = blockIdx.x * blockDim.x + threadIdx.x;
    if (t >= KP) return;
    int ii = rb_in[t];
    if (ii == n_in) return;
    int k = t / P;
    inv[(long)rb_out[t] * K + k] = ii;
}

// ---- weight prep: fp32 [K][ci][co] -> bf16 hi/lo planes, layout [K][co][ci]
// with the LDS XOR swizzle BAKED IN (mconv stages B linearly, reads via swzc).
struct WPE { const float* w; u16* oh; u16* ol; int K, ci, co, total; };
struct WPA { WPE e[9]; };
__global__ void wprep_kernel(WPA a, int grand) {
    int t = blockIdx.x * blockDim.x + threadIdx.x;
    if (t >= grand) return;
    #pragma unroll
    for (int i = 0; i < 9; ++i) {
        if (t < a.e[i].total) {
            const WPE& E = a.e[i];
            int cc = E.ci * E.co;
            int k = t / cc, r = t % cc, c = r / E.co, o = r % E.co;
            float x = E.w[t];
            u16 h = f2bf(x);
            float lf = x - bf2f(h);
            int cs = E.ci >> 3, ph = (cs == 8) ? 0 : 1;
            int ch = c >> 3, e = c & 7;
            int sch = ch ^ ((o >> ph) & (cs - 1));
            long d = ((long)k * E.co + o) * E.ci + sch * 8 + e;
            E.oh[d] = h; E.ol[d] = f2bf(lf);
            return;
        }
        t -= a.e[i].total;
    }
}

// ---- direct tiny-CI conv (layer 0)
template<int CO, int K>
__global__ __launch_bounds__(256)
void dconv4_kernel(const float* __restrict__ feats,   // [n][4]
                   const float* __restrict__ w,       // [K][4][CO]
                   const float* __restrict__ bn,
                   const int* __restrict__ inv,       // [n_out][K]
                   float* __restrict__ out, int n_out) {
    constexpr int OG = CO / 4;
    __shared__ float sW[K * 4 * CO];
    for (int i = threadIdx.x; i < K * 4 * CO; i += 256) sW[i] = w[i];
    __syncthreads();
    long t = (long)blockIdx.x * 256 + threadIdx.x;
    int row = (int)(t / OG), og = (int)(t % OG);
    if (row >= n_out) return;
    float a0 = 0.f, a1 = 0.f, a2 = 0.f, a3 = 0.f;
    for (int k = 0; k < K; ++k) {
        int idx = inv[(long)row * K + k];
        if (idx < 0) continue;
        float4 av = *(const float4*)(feats + (long)idx * 4);
        const float* wk = sW + k * 4 * CO + og * 4;
        #pragma unroll
        for (int ci = 0; ci < 4; ++ci) {
            float a = (&av.x)[ci];
            a0 = fmaf(a, wk[ci * CO + 0], a0);
            a1 = fmaf(a, wk[ci * CO + 1], a1);
            a2 = fmaf(a, wk[ci * CO + 2], a2);
            a3 = fmaf(a, wk[ci * CO + 3], a3);
        }
    }
    float4 g = *(const float4*)(bn + og * 4);
    float4 b = *(const float4*)(bn + CO + og * 4);
    float4 m = *(const float4*)(bn + 2 * CO + og * 4);
    float4 v = *(const float4*)(bn + 3 * CO + og * 4);
    float4 o;
    o.x = fmaxf((a0 - m.x) * rsqrtf(v.x + 1e-3f) * g.x + b.x, 0.f);
    o.y = fmaxf((a1 - m.y) * rsqrtf(v.y + 1e-3f) * g.y + b.y, 0.f);
    o.z = fmaxf((a2 - m.z) * rsqrtf(v.z + 1e-3f) * g.z + b.z, 0.f);
    o.w = fmaxf((a3 - m.w) * rsqrtf(v.w + 1e-3f) * g.w + b.w, 0.f);
    *(float4*)(out + (long)row * CO + og * 4) = o;
}

// ---- fp32 pipelined conv (layers 1-2)
template<int CI, int CO, int TP, int K, bool EMIT16>
__global__ __launch_bounds__(256, 4)
void conv_kernel(const float* __restrict__ feats,
                 const float* __restrict__ w,    // [K][CI][CO]
                 const float* __restrict__ bn,
                 const int* __restrict__ inv,    // [n_out][K]
                 float* __restrict__ out,
                 u16* __restrict__ oh, u16* __restrict__ ol,
                 int n_out) {
    constexpr int OG  = CO / 4;
    constexpr int PTH = 256 / OG;
    constexpr int PT  = TP / PTH;
    constexpr int CIP = CI + 4;
    constexpr int W4  = CI * CO / 4;
    constexpr int WCH = (W4 + 255) / 256;
    constexpr int TR  = CI / 4;
    constexpr int RPS = 256 / TR;
    constexpr int ASW = (TP + RPS - 1) / RPS;

    __shared__ float sW[2][CI * CO];
    __shared__ float sA[2][TP * CIP];
    __shared__ int   sI[TP * K];

    const int brow = blockIdx.x * TP;
    const int t  = threadIdx.x;
    const int og = t % OG;
    const int pg = t / OG;

    {
        long base = (long)brow * K, lim = (long)n_out * K;
        for (int i = t; i < TP * K; i += 256)
            sI[i] = (base + i < lim) ? inv[base + i] : -1;
    }

    float4 wreg[WCH];
    float4 areg[ASW];

    auto load_regs = [&](int k) {
        const float4* src = (const float4*)(w + (long)k * CI * CO);
        #pragma unroll
        for (int c = 0; c < WCH; ++c) {
            int i = c * 256 + t;
            if (W4 >= 256 || i < W4) wreg[c] = src[i];
        }
        #pragma unroll
        for (int s = 0; s < ASW; ++s) {
            int r = s * RPS + t / TR;
            int c = (t % TR) * 4;
            float4 v = make_float4(0.f, 0.f, 0.f, 0.f);
            if (r < TP) {
                int idx = sI[r * K + k];
                if (idx >= 0) v = *(const float4*)(feats + (long)idx * CI + c);
            }
            areg[s] = v;
        }
    };
    auto store_lds = [&](int b) {
        #pragma unroll
        for (int c = 0; c < WCH; ++c) {
            int i = c * 256 + t;
            if (W4 >= 256 || i < W4) ((float4*)sW[b])[i] = wreg[c];
        }
        #pragma unroll
        for (int s = 0; s < ASW; ++s) {
            int r = s * RPS + t / TR;
            int c = (t % TR) * 4;
            if (r < TP) *(float4*)(&sA[b][r * CIP + c]) = areg[s];
        }
    };

    float acc[PT][4];
    #pragma unroll
    for (int i = 0; i < PT; ++i)
        acc[i][0] = acc[i][1] = acc[i][2] = acc[i][3] = 0.f;

    auto compute = [&](int b) {
        #pragma unroll 4
        for (int kk = 0; kk < CI; ++kk) {
            float4 wv = *(const float4*)(&sW[b][kk * CO + og * 4]);
            #pragma unroll
            for (int i = 0; i < PT; ++i) {
                float a = sA[b][(pg * PT + i) * CIP + kk];
                acc[i][0] = fmaf(a, wv.x, acc[i][0]);
                acc[i][1] = fmaf(a, wv.y, acc[i][1]);
                acc[i][2] = fmaf(a, wv.z, acc[i][2]);
                acc[i][3] = fmaf(a, wv.w, acc[i][3]);
            }
        }
    };

    __syncthreads();
    int cur = 0;
    load_regs(0);
    store_lds(0);
    for (int k = 0; k < K; ++k) {
        __syncthreads();
        if (k + 1 < K) load_regs(k + 1);
        compute(cur);
        if (k + 1 < K) store_lds(cur ^ 1);
        cur ^= 1;
    }

    float4 g = *(const float4*)(bn + og * 4);
    float4 b = *(const float4*)(bn + CO + og * 4);
    float4 m = *(const float4*)(bn + 2 * CO + og * 4);
    float4 v = *(const float4*)(bn + 3 * CO + og * 4);
    float s0 = rsqrtf(v.x + 1e-3f) * g.x;
    float s1 = rsqrtf(v.y + 1e-3f) * g.y;
    float s2 = rsqrtf(v.z + 1e-3f) * g.z;
    float s3 = rsqrtf(v.w + 1e-3f) * g.w;
    #pragma unroll
    for (int i = 0; i < PT; ++i) {
        int grow = brow + pg * PT + i;
        if (grow < n_out) {
            float o4[4];
            o4[0] = fmaxf(fmaf(acc[i][0] - m.x, s0, b.x), 0.f);
            o4[1] = fmaxf(fmaf(acc[i][1] - m.y, s1, b.y), 0.f);
            o4[2] = fmaxf(fmaf(acc[i][2] - m.z, s2, b.z), 0.f);
            o4[3] = fmaxf(fmaf(acc[i][3] - m.w, s3, b.w), 0.f);
            if (EMIT16) {
                long base = (long)grow * CO + og * 4;
                #pragma unroll
                for (int c = 0; c < 4; ++c) {
                    u16 h = f2bf(o4[c]);
                    oh[base + c] = h;
                    ol[base + c] = f2bf(o4[c] - bf2f(h));
                }
            } else {
                *(float4*)(out + (long)grow * CO + og * 4) =
                    make_float4(o4[0], o4[1], o4[2], o4[3]);
            }
        }
    }
}

// ---- MFMA sparse conv, global_load_lds staging (no register staging -> no
// spill possible). Single LDS buffer, 2 barriers/tap (m97 structure).
// A gather: per-lane source addr with swizzle pre-applied (m173); sentinel
// rows read a zero page. B: linear sweep of pre-swizzled prepped weights.
// NOTE: staging sweeps use (SL+255)/256 iterations with a slot<SL guard --
// SL is a multiple of 64 so skipped slots are whole waves (uniform branch).
// R8 bug: BSL/256 == 0 for the 32x32 layers left B unstaged.
template<int CI, int CO, int K>
__global__ __launch_bounds__(256, 4)
void mconv_kernel(const u16* __restrict__ fh, const u16* __restrict__ fl,
                  const u16* __restrict__ wh, const u16* __restrict__ wl,
                  const int* __restrict__ inv,
                  const u16* __restrict__ zpage,
                  float* __restrict__ part, long slab_elems,
                  int n_out, int kpb) {
    constexpr int CS  = CI / 8;                // 16B chunks per row
    constexpr int LCS = (CS == 8) ? 3 : 2;     // log2(CS)
    constexpr int PH  = (CS == 8) ? 0 : 1;
    constexpr int KS  = CI / 32;
    constexpr int NTW = CO / 32;
    constexpr int ASL = 64 * CS;               // A slots (16B) per plane
    constexpr int BSL = CO * CS;               // B slots per plane
    constexpr int AIT = (ASL + 255) / 256;
    constexpr int BIT = (BSL + 255) / 256;

    __shared__ __align__(16) u16 sAh[64 * CI];
    __shared__ __align__(16) u16 sAl[64 * CI];
    __shared__ __align__(16) u16 sBh[CO * CI];
    __shared__ __align__(16) u16 sBl[CO * CI];
    __shared__ int sI[64 * K];

    const int t = threadIdx.x;
    const int bx = xcd_swz(blockIdx.x, gridDim.x);
    const int brow = bx * 64;
    const int kbeg = blockIdx.y * kpb;
    const int kend = (kbeg + kpb < K) ? (kbeg + kpb) : K;

    const int lane = t & 63, wid = t >> 6;
    const int wr = wid >> 1, wc = wid & 1;
    const int frow = lane & 15;
    const int fch  = lane >> 4;

    {   // stage inv slice
        long base = (long)brow * K, lim = (long)n_out * K;
        for (int i = t; i < 64 * K; i += 256)
            sI[i] = (base + i < lim) ? inv[base + i] : -1;
    }

    f32x4 acc[2][NTW];
    #pragma unroll
    for (int mt = 0; mt < 2; ++mt)
        #pragma unroll
        for (int nt = 0; nt < NTW; ++nt) {
            acc[mt][nt][0] = 0.f; acc[mt][nt][1] = 0.f;
            acc[mt][nt][2] = 0.f; acc[mt][nt][3] = 0.f;
        }

    __syncthreads();                            // sI ready
    for (int k = kbeg; k < kend; ++k) {
        // ---- stage A: gather via per-lane source, swizzle in the address
        #pragma unroll
        for (int s = 0; s < AIT; ++s) {
            int slot = s * 256 + t;
            if (ASL % 256 == 0 || slot < ASL) {
                int r = slot >> LCS, cc = slot & (CS - 1);
                int c = cc ^ ((r >> PH) & (CS - 1));
                int idx = sI[r * K + k];
                const u16* srcH = (idx >= 0) ? fh + (long)idx * CI + c * 8 : zpage;
                const u16* srcL = (idx >= 0) ? fl + (long)idx * CI + c * 8 : zpage;
                gld16(srcH, sAh + (s * 256 + wid * 64) * 8);
                gld16(srcL, sAl + (s * 256 + wid * 64) * 8);
            }
        }
        // ---- stage B: linear sweep (swizzle baked into global layout)
        {
            const u16* gbh = wh + (long)k * CO * CI;
            const u16* gbl = wl + (long)k * CO * CI;
            #pragma unroll
            for (int s = 0; s < BIT; ++s) {
                int slot = s * 256 + t;
                if (BSL % 256 == 0 || slot < BSL) {
                    gld16(gbh + (long)slot * 8, sBh + (s * 256 + wid * 64) * 8);
                    gld16(gbl + (long)slot * 8, sBl + (s * 256 + wid * 64) * 8);
                }
            }
        }
        __syncthreads();                        // drains vmcnt -> LDS staged

        #pragma unroll
        for (int ks = 0; ks < KS; ++ks) {
            int c = ks * 4 + fch;
            short8v ah[2], al[2];
            #pragma unroll
            for (int mt = 0; mt < 2; ++mt) {
                int r = wr * 32 + mt * 16 + frow;
                int o = r * CI + swzc<CS>(r, c) * 8;
                ah[mt] = *(const short8v*)(sAh + o);
                al[mt] = *(const short8v*)(sAl + o);
            }
            #pragma unroll
            for (int nt = 0; nt < NTW; ++nt) {
                int col = wc * (CO / 2) + nt * 16 + frow;
                int o = col * CI + swzc<CS>(col, c) * 8;
                short8v bh = *(const short8v*)(sBh + o);
                short8v bl = *(const short8v*)(sBl + o);
                #pragma unroll
                for (int mt = 0; mt < 2; ++mt) {
                    acc[mt][nt] = __builtin_amdgcn_mfma_f32_16x16x32_bf16(ah[mt], bh, acc[mt][nt], 0, 0, 0);
                    acc[mt][nt] = __builtin_amdgcn_mfma_f32_16x16x32_bf16(ah[mt], bl, acc[mt][nt], 0, 0, 0);
                    acc[mt][nt] = __builtin_amdgcn_mfma_f32_16x16x32_bf16(al[mt], bh, acc[mt][nt], 0, 0, 0);
                }
            }
        }
        if (k + 1 < kend) __syncthreads();      // before next tap overwrites LDS
    }

    float* dst = part + (long)blockIdx.y * slab_elems;
    #pragma unroll
    for (int mt = 0; mt < 2; ++mt) {
        int orow0 = brow + wr * 32 + mt * 16 + (lane >> 4) * 4;
        #pragma unroll
        for (int nt = 0; nt < NTW; ++nt) {
            int ocol = wc * (CO / 2) + nt * 16 + (lane & 15);
            #pragma unroll
            for (int j = 0; j < 4; ++j) {
                int r = orow0 + j;
                if (r < n_out) dst[(long)r * CO + ocol] = acc[mt][nt][j];
            }
        }
    }
}

// ---- slab reduce + BN + ReLU (+ bf16 hi/lo emit OR fp32 out)
template<bool EMIT16>
__global__ void reduce_bnrelu_kernel(const float* __restrict__ part, long stride,
                                     int ys, const float* __restrict__ bn, int co,
                                     float* __restrict__ outf,
                                     u16* __restrict__ oh, u16* __restrict__ ol,
                                     long total) {
    long t = (long)blockIdx.x * blockDim.x + threadIdx.x;
    if (t >= total) return;
    float s = 0.f;
    for (int y = 0; y < ys; ++y) s += part[(long)y * stride + t];
    int o = (int)(t % co);
    float g = bn[o], b = bn[co + o], m = bn[2 * co + o], v = bn[3 * co + o];
    float yv = fmaxf((s - m) * rsqrtf(v + 1e-3f) * g + b, 0.f);
    if (EMIT16) {
        u16 h = f2bf(yv);
        oh[t] = h;
        ol[t] = f2bf(yv - bf2f(h));
    } else {
        outf[t] = yv;
    }
}

// ---- per-batch max pool
__global__ void segmax_kernel(const float* __restrict__ x,
                              const int* __restrict__ bidx,
                              float* __restrict__ out, int rows, int nb) {
    __shared__ float sM[8 * 128];
    for (int i = threadIdx.x; i < nb * 128; i += 256) sM[i] = 0.f;
    __syncthreads();
    int c = threadIdx.x & 127;
    int sub = threadIdx.x >> 7;
    for (int r = blockIdx.x * 2 + sub; r < rows; r += gridDim.x * 2) {
        float v = x[(long)r * 128 + c];
        int b = bidx[r];
        atomicMax((int*)&sM[b * 128 + c], __float_as_int(v));
    }
    __syncthreads();
    for (int i = threadIdx.x; i < nb * 128; i += 256)
        atomicMax((int*)out + i, __float_as_int(sM[i]));
}

extern "C" void kernel_launch(void* const* d_in, const int* in_sizes, int n_in,
                              void* d_out, int out_size, void* d_ws, size_t ws_size,
                              hipStream_t stream) {
    (void)n_in;
    const float* voxels = (const float*)d_in[24];
    const int*   nump   = (const int*)d_in[25];
    const int N  = in_sizes[25];
    const int n2 = in_sizes[30] / 27;
    const int n3 = in_sizes[34] / 27;
    const int n4 = in_sizes[38] / 27;
    const int n5 = in_sizes[42];

    struct L { int wi, rb, K, ci, co, nin, nout; };
    const L layers[12] = {
        {0,  26, 27,  4,  16, N,  N }, {1,  26, 27, 16,  16, N,  N },
        {2,  28, 27, 16,  32, N,  n2}, {3,  30, 27, 32,  32, n2, n2},
        {4,  30, 27, 32,  32, n2, n2}, {5,  32, 27, 32,  64, n2, n3},
        {6,  34, 27, 64,  64, n3, n3}, {7,  34, 27, 64,  64, n3, n3},
        {8,  36, 27, 64,  64, n3, n4}, {9,  38, 27, 64,  64, n4, n4},
        {10, 38, 27, 64,  64, n4, n4}, {11, 40,  3, 64, 128, n4, n5},
    };

    // ---- workspace carve-up (fixed part), remainder = split-K slab budget
    size_t inv_elems = 0, feat_elems = (size_t)N * 4, wt_elems = 0;
    for (int i = 0; i < 12; ++i) {
        size_t ie = (size_t)layers[i].nout * layers[i].K;
        size_t fe = (size_t)layers[i].nout * layers[i].co;
        if (ie > inv_elems)  inv_elems  = ie;
        if (fe > feat_elems) feat_elems = fe;
        if (i >= 3) wt_elems += (size_t)layers[i].K * layers[i].ci * layers[i].co;
    }
    auto al = [](size_t x) { return (x + 255) & ~(size_t)255; };
    char* p = (char*)d_ws;
    u16*   zpage = (u16*)p; p += 256;
    int*   inv  = (int*)p;   p += al(inv_elems * 4);
    float* bufA = (float*)p; p += al(feat_elems * 4);
    float* bufB = (float*)p; p += al(feat_elems * 4);
    u16* ph[2]; u16* pl[2];
    ph[0] = (u16*)p; p += al(feat_elems * 2);
    pl[0] = (u16*)p; p += al(feat_elems * 2);
    ph[1] = (u16*)p; p += al(feat_elems * 2);
    pl[1] = (u16*)p; p += al(feat_elems * 2);
    u16* wth = (u16*)p; p += al(wt_elems * 2);
    u16* wtl = (u16*)p; p += al(wt_elems * 2);
    float* slab = (float*)p;
    size_t slab_budget = ws_size - (size_t)((char*)slab - (char*)d_ws);

    hipMemsetAsync(zpage, 0, 256, stream);      // sentinel zero page

    // ---- VFE
    {
        long tot = (long)N * 4;
        vfe_kernel<<<dim3((unsigned)((tot + TPB - 1) / TPB)), dim3(TPB), 0, stream>>>(
            voxels, nump, bufA, N);
    }

    // ---- weight prep for MFMA layers
    size_t woff[9];
    {
        WPA wa;
        size_t off = 0;
        for (int i = 0; i < 9; ++i) {
            const L& l = layers[i + 3];
            woff[i] = off;
            wa.e[i].w  = (const float*)d_in[2 * l.wi];
            wa.e[i].oh = wth + off;
            wa.e[i].ol = wtl + off;
            wa.e[i].K = l.K; wa.e[i].ci = l.ci; wa.e[i].co = l.co;
            wa.e[i].total = l.K * l.ci * l.co;
            off += (size_t)wa.e[i].total;
        }
        int grand = (int)off;
        wprep_kernel<<<dim3((grand + TPB - 1) / TPB), dim3(TPB), 0, stream>>>(wa, grand);
    }

    int prev_rb = -1;
    auto build_inv = [&](const L& l) {
        if (l.rb == prev_rb) return;
        const int* rin  = (const int*)d_in[l.rb];
        const int* rout = (const int*)d_in[l.rb + 1];
        int P  = in_sizes[l.rb] / l.K;
        int KP = l.K * P;
        hipMemsetAsync(inv, 0xFF, (size_t)l.nout * l.K * sizeof(int), stream);
        inv_build_kernel<<<dim3((KP + TPB - 1) / TPB), dim3(TPB), 0, stream>>>(
            rin, rout, inv, KP, P, l.K, l.nin);
        prev_rb = l.rb;
    };

    // ---- layer 0: direct tiny-CI kernel
    {
        const L& l = layers[0];
        build_inv(l);
        long tot = (long)l.nout * 4;
        dconv4_kernel<16, 27><<<dim3((unsigned)((tot + 255) / 256)), 256, 0, stream>>>(
            bufA, (const float*)d_in[0], (const float*)d_in[1], inv, bufB, l.nout);
    }
    // ---- layers 1-2: fp32 pipelined template
    {
        const L& l = layers[1];
        build_inv(l);
        conv_kernel<16, 16, 64, 27, false><<<dim3((l.nout + 63) / 64), 256, 0, stream>>>(
            bufB, (const float*)d_in[2], (const float*)d_in[3], inv,
            bufA, nullptr, nullptr, l.nout);
    }
    {
        const L& l = layers[2];
        build_inv(l);
        conv_kernel<16, 32, 64, 27, true><<<dim3((l.nout + 63) / 64), 256, 0, stream>>>(
            bufA, (const float*)d_in[4], (const float*)d_in[5], inv,
            nullptr, ph[0], pl[0], l.nout);
    }

    // ---- MFMA layers 3-11 (split-K sized to fill the chip, slab-budgeted)
    int cset = 0;
    for (int i = 3; i < 12; ++i) {
        const L& l = layers[i];
        build_inv(l);
        unsigned blocks = (unsigned)((l.nout + 63) / 64);
        int ys = 1;
        int ys_max = (l.K == 27) ? 27 : 3;
        while (ys < ys_max && blocks * (unsigned)ys < 768) ys *= 3;
        size_t per = (size_t)l.nout * l.co * 4;
        while (ys > 1 && (size_t)ys * per > slab_budget) ys /= 3;
        int kpb = (l.K + ys - 1) / ys;
        long slab_elems = (long)l.nout * l.co;
        dim3 grid(blocks, (unsigned)ys);
        const u16* fh = ph[cset];
        const u16* fl = pl[cset];
        const u16* whp = wth + woff[i - 3];
        const u16* wlp = wtl + woff[i - 3];

        switch (i) {
        case 3: case 4:
            mconv_kernel<32, 32, 27><<<grid, 256, 0, stream>>>(
                fh, fl, whp, wlp, inv, zpage, slab, slab_elems, l.nout, kpb); break;
        case 5:
            mconv_kernel<32, 64, 27><<<grid, 256, 0, stream>>>(
                fh, fl, whp, wlp, inv, zpage, slab, slab_elems, l.nout, kpb); break;
        case 11:
            mconv_kernel<64, 128, 3><<<grid, 256, 0, stream>>>(
                fh, fl, whp, wlp, inv, zpage, slab, slab_elems, l.nout, kpb); break;
        default:
            mconv_kernel<64, 64, 27><<<grid, 256, 0, stream>>>(
                fh, fl, whp, wlp, inv, zpage, slab, slab_elems, l.nout, kpb); break;
        }

        long total = (long)l.nout * l.co;
        unsigned rblocks = (unsigned)((total + TPB - 1) / TPB);
        const float* bn = (const float*)d_in[2 * l.wi + 1];
        if (i < 11) {
            reduce_bnrelu_kernel<true><<<dim3(rblocks), dim3(TPB), 0, stream>>>(
                slab, slab_elems, ys, bn, l.co,
                nullptr, ph[cset ^ 1], pl[cset ^ 1], total);
            cset ^= 1;
        } else {
            reduce_bnrelu_kernel<false><<<dim3(rblocks), dim3(TPB), 0, stream>>>(
                slab, slab_elems, ys, bn, l.co, bufA, nullptr, nullptr, total);
        }
    }

    // ---- segment max
    hipMemsetAsync(d_out, 0, (size_t)out_size * sizeof(float), stream);
    const int* bidx = (const int*)d_in[42];
    int nb = out_size / 128;
    segmax_kernel<<<dim3(128), dim3(256), 0, stream>>>(bufA, bidx, (float*)d_out, n5, nb);
}

// Round 10
// 473.349 us; speedup vs baseline: 1.5009x; 1.0671x over previous
//
#include <hip/hip_runtime.h>

#define TPB 256
typedef unsigned short u16;
typedef __attribute__((ext_vector_type(8))) short short8v;
typedef __attribute__((ext_vector_type(4))) float f32x4;

__device__ __forceinline__ u16 f2bf(float x) {
    unsigned u = __float_as_uint(x);
    return (u16)((u + 0x7FFFu + ((u >> 16) & 1u)) >> 16);
}
__device__ __forceinline__ float bf2f(u16 h) {
    return __uint_as_float(((unsigned)h) << 16);
}

// LDS 16B-chunk XOR swizzle (CS = chunks per row = CI/8).
template<int CS>
__device__ __forceinline__ int swzc(int r, int c) {
    constexpr int PH = (CS == 8) ? 0 : 1;   // CS==8: 128B rows, CS==4: 64B rows
    return c ^ ((r >> PH) & (CS - 1));
}

// bijective XCD-contiguity swizzle (m204)
__device__ __forceinline__ int xcd_swz(int bid, int nwg) {
    int q = nwg >> 3, r = nwg & 7;
    int x = bid & 7, idx = bid >> 3;
    return (x < r ? x * (q + 1) : r * (q + 1) + (x - r) * q) + idx;
}

// async global->LDS, 16B per lane; LDS dest = wave-uniform base + lane*16
__device__ __forceinline__ void gld16(const u16* g, u16* l) {
    __builtin_amdgcn_global_load_lds(
        (const __attribute__((address_space(1))) void*)g,
        (__attribute__((address_space(3))) void*)l, 16, 0, 0);
}

// ---- mean-VFE
__global__ void vfe_kernel(const float* __restrict__ voxels,
                           const int* __restrict__ nump,
                           float* __restrict__ x, int N) {
    int i = blockIdx.x * blockDim.x + threadIdx.x;
    if (i >= N * 4) return;
    int n = i >> 2, c = i & 3;
    const float* v = voxels + (long)n * 20 + c;
    float s = v[0] + v[4] + v[8] + v[12] + v[16];
    x[i] = s / fmaxf((float)nump[n], 1.0f);
}

// ---- invert rulebook: inv[out_row][k] = in_row (or -1)
__global__ void inv_build_kernel(const int* __restrict__ rb_in,
                                 const int* __restrict__ rb_out,
                                 int* __restrict__ inv,
                                 int KP, int P, int K, int n_in) {
    int t = blockIdx.x * blockDim.x + threadIdx.x;
    if (t >= KP) return;
    int ii = rb_in[t];
    if (ii == n_in) return;
    int k = t / P;
    inv[(long)rb_out[t] * K + k] = ii;
}

// ---- weight prep (layers 3-11): fp32 [K][ci][co] -> bf16 hi/lo, [K][co][ci],
// LDS XOR swizzle baked in.
struct WPE { const float* w; u16* oh; u16* ol; int K, ci, co, total; };
struct WPA { WPE e[9]; };
__global__ void wprep_kernel(WPA a, int grand) {
    int t = blockIdx.x * blockDim.x + threadIdx.x;
    if (t >= grand) return;
    #pragma unroll
    for (int i = 0; i < 9; ++i) {
        if (t < a.e[i].total) {
            const WPE& E = a.e[i];
            int cc = E.ci * E.co;
            int k = t / cc, r = t % cc, c = r / E.co, o = r % E.co;
            float x = E.w[t];
            u16 h = f2bf(x);
            float lf = x - bf2f(h);
            int cs = E.ci >> 3, ph = (cs == 8) ? 0 : 1;
            int ch = c >> 3, e = c & 7;
            int sch = ch ^ ((o >> ph) & (cs - 1));
            long d = ((long)k * E.co + o) * E.ci + sch * 8 + e;
            E.oh[d] = h; E.ol[d] = f2bf(lf);
            return;
        }
        t -= a.e[i].total;
    }
}

// ---- paired weight prep (layers 1-2, ci=16): fp32 [27][16][co] ->
// bf16 hi/lo [14][co][32] (two taps concatenated on the reduction axis,
// pseudo-tap 13 second half zero-padded), swizzle baked in (cs=4, ph=1).
// Output-indexed so the pad is written.
__global__ void wprep_paired_kernel(const float* __restrict__ w,
                                    u16* __restrict__ oh, u16* __restrict__ ol,
                                    int co, int total) {
    int t = blockIdx.x * blockDim.x + threadIdx.x;
    if (t >= total) return;
    int p = t / (co * 32);
    int rem = t % (co * 32);
    int o = rem / 32, ci = rem % 32;
    int tap = 2 * p + (ci >> 4);
    float x = (tap < 27) ? w[((long)tap * 16 + (ci & 15)) * co + o] : 0.f;
    u16 h = f2bf(x);
    float lf = x - bf2f(h);
    int ch = ci >> 3, e = ci & 7;
    int sch = ch ^ ((o >> 1) & 3);
    long d = ((long)p * co + o) * 32 + sch * 8 + e;
    oh[d] = h; ol[d] = f2bf(lf);
}

// ---- direct tiny-CI conv (layer 0), emits bf16 hi/lo planes
template<int CO, int K>
__global__ __launch_bounds__(256)
void dconv4_kernel(const float* __restrict__ feats,   // [n][4]
                   const float* __restrict__ w,       // [K][4][CO]
                   const float* __restrict__ bn,
                   const int* __restrict__ inv,       // [n_out][K]
                   u16* __restrict__ oh, u16* __restrict__ ol,
                   int n_out) {
    constexpr int OG = CO / 4;
    __shared__ float sW[K * 4 * CO];
    for (int i = threadIdx.x; i < K * 4 * CO; i += 256) sW[i] = w[i];
    __syncthreads();
    long t = (long)blockIdx.x * 256 + threadIdx.x;
    int row = (int)(t / OG), og = (int)(t % OG);
    if (row >= n_out) return;
    float a0 = 0.f, a1 = 0.f, a2 = 0.f, a3 = 0.f;
    for (int k = 0; k < K; ++k) {
        int idx = inv[(long)row * K + k];
        if (idx < 0) continue;
        float4 av = *(const float4*)(feats + (long)idx * 4);
        const float* wk = sW + k * 4 * CO + og * 4;
        #pragma unroll
        for (int ci = 0; ci < 4; ++ci) {
            float a = (&av.x)[ci];
            a0 = fmaf(a, wk[ci * CO + 0], a0);
            a1 = fmaf(a, wk[ci * CO + 1], a1);
            a2 = fmaf(a, wk[ci * CO + 2], a2);
            a3 = fmaf(a, wk[ci * CO + 3], a3);
        }
    }
    float4 g = *(const float4*)(bn + og * 4);
    float4 b = *(const float4*)(bn + CO + og * 4);
    float4 m = *(const float4*)(bn + 2 * CO + og * 4);
    float4 v = *(const float4*)(bn + 3 * CO + og * 4);
    float o4[4];
    o4[0] = fmaxf((a0 - m.x) * rsqrtf(v.x + 1e-3f) * g.x + b.x, 0.f);
    o4[1] = fmaxf((a1 - m.y) * rsqrtf(v.y + 1e-3f) * g.y + b.y, 0.f);
    o4[2] = fmaxf((a2 - m.z) * rsqrtf(v.z + 1e-3f) * g.z + b.z, 0.f);
    o4[3] = fmaxf((a3 - m.w) * rsqrtf(v.w + 1e-3f) * g.w + b.w, 0.f);
    long base = (long)row * CO + og * 4;
    #pragma unroll
    for (int c = 0; c < 4; ++c) {
        u16 h = f2bf(o4[c]);
        oh[base + c] = h;
        ol[base + c] = f2bf(o4[c] - bf2f(h));
    }
}

// ---- MFMA sparse conv, global_load_lds staging, single LDS buffer,
// 2 barriers/tap. XOR swizzle applied at the A source address / baked into
// B's global layout; swizzled reads. Split-K partials to slab blockIdx.y.
// PAIRED: per-tap ci=16, two taps fused per 32-wide MFMA K-step; KP
// pseudo-taps over KT real taps; pad tap reads zpage (weights pre-zeroed).
// Wave geometry adapts to CO: CO>=32 -> 2x2 wave grid, CO==16 -> 4x1.
template<int CI, int CO, int KP, int KT, bool PAIRED>
__global__ __launch_bounds__(256, 4)
void mconv_kernel(const u16* __restrict__ fh, const u16* __restrict__ fl,
                  const u16* __restrict__ wh, const u16* __restrict__ wl,
                  const int* __restrict__ inv,
                  const u16* __restrict__ zpage,
                  float* __restrict__ part, long slab_elems,
                  int n_out, int kpb) {
    constexpr int CS  = CI / 8;                // 16B chunks per row
    constexpr int LCS = (CS == 8) ? 3 : 2;
    constexpr int PH  = (CS == 8) ? 0 : 1;
    constexpr int KS  = CI / 32;
    constexpr int WC  = (CO >= 32) ? 2 : 1;    // wave cols
    constexpr int MT  = (WC == 2) ? 2 : 1;     // 16-row tiles per wave
    constexpr int NTW = CO / (16 * WC);        // 16-col tiles per wave
    constexpr int ASL = 64 * CS;
    constexpr int BSL = CO * CS;
    constexpr int AIT = (ASL + 255) / 256;
    constexpr int BIT = (BSL + 255) / 256;

    __shared__ __align__(16) u16 sAh[64 * CI];
    __shared__ __align__(16) u16 sAl[64 * CI];
    __shared__ __align__(16) u16 sBh[CO * CI];
    __shared__ __align__(16) u16 sBl[CO * CI];
    __shared__ int sI[64 * KT];

    const int t = threadIdx.x;
    const int bx = xcd_swz(blockIdx.x, gridDim.x);
    const int brow = bx * 64;
    const int kbeg = blockIdx.y * kpb;
    const int kend = (kbeg + kpb < KP) ? (kbeg + kpb) : KP;

    const int lane = t & 63, wid = t >> 6;
    const int wr = wid / WC, wc = wid % WC;
    const int frow = lane & 15;
    const int fch  = lane >> 4;

    {   // stage inv slice
        long base = (long)brow * KT, lim = (long)n_out * KT;
        for (int i = t; i < 64 * KT; i += 256)
            sI[i] = (base + i < lim) ? inv[base + i] : -1;
    }

    f32x4 acc[MT][NTW];
    #pragma unroll
    for (int mt = 0; mt < MT; ++mt)
        #pragma unroll
        for (int nt = 0; nt < NTW; ++nt) {
            acc[mt][nt][0] = 0.f; acc[mt][nt][1] = 0.f;
            acc[mt][nt][2] = 0.f; acc[mt][nt][3] = 0.f;
        }

    __syncthreads();                            // sI ready
    for (int k = kbeg; k < kend; ++k) {
        // ---- stage A: gather, swizzle pre-applied to the source address
        #pragma unroll
        for (int s = 0; s < AIT; ++s) {
            int slot = s * 256 + t;
            if (ASL % 256 == 0 || slot < ASL) {
                int r = slot >> LCS, cc = slot & (CS - 1);
                int c = cc ^ ((r >> PH) & (CS - 1));
                const u16 *srcH, *srcL;
                if (PAIRED) {
                    int tap = 2 * k + (c >> 1);
                    int idx = (tap < KT) ? sI[r * KT + tap] : -1;
                    srcH = (idx >= 0) ? fh + (long)idx * 16 + (c & 1) * 8 : zpage;
                    srcL = (idx >= 0) ? fl + (long)idx * 16 + (c & 1) * 8 : zpage;
                } else {
                    int idx = sI[r * KT + k];
                    srcH = (idx >= 0) ? fh + (long)idx * CI + c * 8 : zpage;
                    srcL = (idx >= 0) ? fl + (long)idx * CI + c * 8 : zpage;
                }
                gld16(srcH, sAh + (s * 256 + wid * 64) * 8);
                gld16(srcL, sAl + (s * 256 + wid * 64) * 8);
            }
        }
        // ---- stage B: linear sweep (swizzle baked into global layout)
        {
            const u16* gbh = wh + (long)k * CO * CI;
            const u16* gbl = wl + (long)k * CO * CI;
            #pragma unroll
            for (int s = 0; s < BIT; ++s) {
                int slot = s * 256 + t;
                if (BSL % 256 == 0 || slot < BSL) {
                    gld16(gbh + (long)slot * 8, sBh + (s * 256 + wid * 64) * 8);
                    gld16(gbl + (long)slot * 8, sBl + (s * 256 + wid * 64) * 8);
                }
            }
        }
        __syncthreads();                        // drains vmcnt -> LDS staged

        #pragma unroll
        for (int ks = 0; ks < KS; ++ks) {
            int c = ks * 4 + fch;
            short8v ah[MT], al[MT];
            #pragma unroll
            for (int mt = 0; mt < MT; ++mt) {
                int r = wr * (MT * 16) + mt * 16 + frow;
                int o = r * CI + swzc<CS>(r, c) * 8;
                ah[mt] = *(const short8v*)(sAh + o);
                al[mt] = *(const short8v*)(sAl + o);
            }
            #pragma unroll
            for (int nt = 0; nt < NTW; ++nt) {
                int col = wc * (CO / WC) + nt * 16 + frow;
                int o = col * CI + swzc<CS>(col, c) * 8;
                short8v bh = *(const short8v*)(sBh + o);
                short8v bl = *(const short8v*)(sBl + o);
                #pragma unroll
                for (int mt = 0; mt < MT; ++mt) {
                    acc[mt][nt] = __builtin_amdgcn_mfma_f32_16x16x32_bf16(ah[mt], bh, acc[mt][nt], 0, 0, 0);
                    acc[mt][nt] = __builtin_amdgcn_mfma_f32_16x16x32_bf16(ah[mt], bl, acc[mt][nt], 0, 0, 0);
                    acc[mt][nt] = __builtin_amdgcn_mfma_f32_16x16x32_bf16(al[mt], bh, acc[mt][nt], 0, 0, 0);
                }
            }
        }
        if (k + 1 < kend) __syncthreads();      // before next tap overwrites LDS
    }

    float* dst = part + (long)blockIdx.y * slab_elems;
    #pragma unroll
    for (int mt = 0; mt < MT; ++mt) {
        int orow0 = brow + wr * (MT * 16) + mt * 16 + (lane >> 4) * 4;
        #pragma unroll
        for (int nt = 0; nt < NTW; ++nt) {
            int ocol = wc * (CO / WC) + nt * 16 + (lane & 15);
            #pragma unroll
            for (int j = 0; j < 4; ++j) {
                int r = orow0 + j;
                if (r < n_out) dst[(long)r * CO + ocol] = acc[mt][nt][j];
            }
        }
    }
}

// ---- slab reduce + BN + ReLU (+ bf16 hi/lo emit OR fp32 out)
template<bool EMIT16>
__global__ void reduce_bnrelu_kernel(const float* __restrict__ part, long stride,
                                     int ys, const float* __restrict__ bn, int co,
                                     float* __restrict__ outf,
                                     u16* __restrict__ oh, u16* __restrict__ ol,
                                     long total) {
    long t = (long)blockIdx.x * blockDim.x + threadIdx.x;
    if (t >= total) return;
    float s = 0.f;
    for (int y = 0; y < ys; ++y) s += part[(long)y * stride + t];
    int o = (int)(t % co);
    float g = bn[o], b = bn[co + o], m = bn[2 * co + o], v = bn[3 * co + o];
    float yv = fmaxf((s - m) * rsqrtf(v + 1e-3f) * g + b, 0.f);
    if (EMIT16) {
        u16 h = f2bf(yv);
        oh[t] = h;
        ol[t] = f2bf(yv - bf2f(h));
    } else {
        outf[t] = yv;
    }
}

// ---- per-batch max pool
__global__ void segmax_kernel(const float* __restrict__ x,
                              const int* __restrict__ bidx,
                              float* __restrict__ out, int rows, int nb) {
    __shared__ float sM[8 * 128];
    for (int i = threadIdx.x; i < nb * 128; i += 256) sM[i] = 0.f;
    __syncthreads();
    int c = threadIdx.x & 127;
    int sub = threadIdx.x >> 7;
    for (int r = blockIdx.x * 2 + sub; r < rows; r += gridDim.x * 2) {
        float v = x[(long)r * 128 + c];
        int b = bidx[r];
        atomicMax((int*)&sM[b * 128 + c], __float_as_int(v));
    }
    __syncthreads();
    for (int i = threadIdx.x; i < nb * 128; i += 256)
        atomicMax((int*)out + i, __float_as_int(sM[i]));
}

extern "C" void kernel_launch(void* const* d_in, const int* in_sizes, int n_in,
                              void* d_out, int out_size, void* d_ws, size_t ws_size,
                              hipStream_t stream) {
    (void)n_in;
    const float* voxels = (const float*)d_in[24];
    const int*   nump   = (const int*)d_in[25];
    const int N  = in_sizes[25];
    const int n2 = in_sizes[30] / 27;
    const int n3 = in_sizes[34] / 27;
    const int n4 = in_sizes[38] / 27;
    const int n5 = in_sizes[42];

    struct L { int wi, rb, K, ci, co, nin, nout; };
    const L layers[12] = {
        {0,  26, 27,  4,  16, N,  N }, {1,  26, 27, 16,  16, N,  N },
        {2,  28, 27, 16,  32, N,  n2}, {3,  30, 27, 32,  32, n2, n2},
        {4,  30, 27, 32,  32, n2, n2}, {5,  32, 27, 32,  64, n2, n3},
        {6,  34, 27, 64,  64, n3, n3}, {7,  34, 27, 64,  64, n3, n3},
        {8,  36, 27, 64,  64, n3, n4}, {9,  38, 27, 64,  64, n4, n4},
        {10, 38, 27, 64,  64, n4, n4}, {11, 40,  3, 64, 128, n4, n5},
    };

    // ---- workspace carve-up (fixed part), remainder = split-K slab budget
    size_t inv_elems = 0, feat_elems = (size_t)N * 4, wt_elems = 0;
    for (int i = 0; i < 12; ++i) {
        size_t ie = (size_t)layers[i].nout * layers[i].K;
        size_t fe = (size_t)layers[i].nout * layers[i].co;
        if (ie > inv_elems)  inv_elems  = ie;
        if (fe > feat_elems) feat_elems = fe;
        if (i >= 3) wt_elems += (size_t)layers[i].K * layers[i].ci * layers[i].co;
    }
    const size_t wp1_elems = 14 * 32 * 16;   // paired L1 weights
    const size_t wp2_elems = 14 * 32 * 32;   // paired L2 weights
    auto al = [](size_t x) { return (x + 255) & ~(size_t)255; };
    char* p = (char*)d_ws;
    u16*   zpage = (u16*)p; p += 256;
    int*   inv  = (int*)p;   p += al(inv_elems * 4);
    float* bufA = (float*)p; p += al(feat_elems * 4);
    u16* ph[2]; u16* pl[2];
    ph[0] = (u16*)p; p += al(feat_elems * 2);
    pl[0] = (u16*)p; p += al(feat_elems * 2);
    ph[1] = (u16*)p; p += al(feat_elems * 2);
    pl[1] = (u16*)p; p += al(feat_elems * 2);
    u16* wth = (u16*)p; p += al(wt_elems * 2);
    u16* wtl = (u16*)p; p += al(wt_elems * 2);
    u16* wp1h = (u16*)p; p += al(wp1_elems * 2);
    u16* wp1l = (u16*)p; p += al(wp1_elems * 2);
    u16* wp2h = (u16*)p; p += al(wp2_elems * 2);
    u16* wp2l = (u16*)p; p += al(wp2_elems * 2);
    float* slab = (float*)p;
    size_t slab_budget = ws_size - (size_t)((char*)slab - (char*)d_ws);

    hipMemsetAsync(zpage, 0, 256, stream);      // sentinel zero page

    // ---- VFE
    {
        long tot = (long)N * 4;
        vfe_kernel<<<dim3((unsigned)((tot + TPB - 1) / TPB)), dim3(TPB), 0, stream>>>(
            voxels, nump, bufA, N);
    }

    // ---- weight prep (layers 3-11) + paired prep (layers 1-2)
    size_t woff[9];
    {
        WPA wa;
        size_t off = 0;
        for (int i = 0; i < 9; ++i) {
            const L& l = layers[i + 3];
            woff[i] = off;
            wa.e[i].w  = (const float*)d_in[2 * l.wi];
            wa.e[i].oh = wth + off;
            wa.e[i].ol = wtl + off;
            wa.e[i].K = l.K; wa.e[i].ci = l.ci; wa.e[i].co = l.co;
            wa.e[i].total = l.K * l.ci * l.co;
            off += (size_t)wa.e[i].total;
        }
        int grand = (int)off;
        wprep_kernel<<<dim3((grand + TPB - 1) / TPB), dim3(TPB), 0, stream>>>(wa, grand);
        wprep_paired_kernel<<<dim3(((int)wp1_elems + TPB - 1) / TPB), dim3(TPB), 0, stream>>>(
            (const float*)d_in[2], wp1h, wp1l, 16, (int)wp1_elems);
        wprep_paired_kernel<<<dim3(((int)wp2_elems + TPB - 1) / TPB), dim3(TPB), 0, stream>>>(
            (const float*)d_in[4], wp2h, wp2l, 32, (int)wp2_elems);
    }

    int prev_rb = -1;
    auto build_inv = [&](const L& l) {
        if (l.rb == prev_rb) return;
        const int* rin  = (const int*)d_in[l.rb];
        const int* rout = (const int*)d_in[l.rb + 1];
        int P  = in_sizes[l.rb] / l.K;
        int KP = l.K * P;
        hipMemsetAsync(inv, 0xFF, (size_t)l.nout * l.K * sizeof(int), stream);
        inv_build_kernel<<<dim3((KP + TPB - 1) / TPB), dim3(TPB), 0, stream>>>(
            rin, rout, inv, KP, P, l.K, l.nin);
        prev_rb = l.rb;
    };

    // pick split-K factor so blocks*ys fills the chip, capped by slab budget
    auto pick_ys = [&](unsigned blocks, int ys_max, size_t per) {
        int ys = 1;
        while (ys < ys_max && blocks * (unsigned)ys < 768) ys *= 3;
        if (ys > ys_max) ys = ys_max;
        while (ys > 1 && (size_t)ys * per > slab_budget) ys /= 3;
        return ys;
    };

    // ---- layer 0: direct tiny-CI kernel, emits planes -> set 0
    {
        const L& l = layers[0];
        build_inv(l);
        long tot = (long)l.nout * 4;
        dconv4_kernel<16, 27><<<dim3((unsigned)((tot + 255) / 256)), 256, 0, stream>>>(
            bufA, (const float*)d_in[0], (const float*)d_in[1], inv,
            ph[0], pl[0], l.nout);
    }

    // ---- layers 1-2: paired MFMA (14 pseudo-taps over 27)
    int cset = 0;
    for (int i = 1; i < 3; ++i) {
        const L& l = layers[i];
        build_inv(l);
        unsigned blocks = (unsigned)((l.nout + 63) / 64);
        size_t per = (size_t)l.nout * l.co * 4;
        int ys = pick_ys(blocks, 3, per);
        int kpb = (14 + ys - 1) / ys;
        long slab_elems = (long)l.nout * l.co;
        dim3 grid(blocks, (unsigned)ys);
        if (i == 1)
            mconv_kernel<32, 16, 14, 27, true><<<grid, 256, 0, stream>>>(
                ph[cset], pl[cset], wp1h, wp1l, inv, zpage,
                slab, slab_elems, l.nout, kpb);
        else
            mconv_kernel<32, 32, 14, 27, true><<<grid, 256, 0, stream>>>(
                ph[cset], pl[cset], wp2h, wp2l, inv, zpage,
                slab, slab_elems, l.nout, kpb);
        long total = (long)l.nout * l.co;
        unsigned rblocks = (unsigned)((total + TPB - 1) / TPB);
        reduce_bnrelu_kernel<true><<<dim3(rblocks), dim3(TPB), 0, stream>>>(
            slab, slab_elems, ys, (const float*)d_in[2 * l.wi + 1], l.co,
            nullptr, ph[cset ^ 1], pl[cset ^ 1], total);
        cset ^= 1;
    }

    // ---- MFMA layers 3-11
    for (int i = 3; i < 12; ++i) {
        const L& l = layers[i];
        build_inv(l);
        unsigned blocks = (unsigned)((l.nout + 63) / 64);
        size_t per = (size_t)l.nout * l.co * 4;
        int ys = pick_ys(blocks, (l.K == 27) ? 27 : 3, per);
        int kpb = (l.K + ys - 1) / ys;
        long slab_elems = (long)l.nout * l.co;
        dim3 grid(blocks, (unsigned)ys);
        const u16* fh = ph[cset];
        const u16* fl = pl[cset];
        const u16* whp = wth + woff[i - 3];
        const u16* wlp = wtl + woff[i - 3];

        switch (i) {
        case 3: case 4:
            mconv_kernel<32, 32, 27, 27, false><<<grid, 256, 0, stream>>>(
                fh, fl, whp, wlp, inv, zpage, slab, slab_elems, l.nout, kpb); break;
        case 5:
            mconv_kernel<32, 64, 27, 27, false><<<grid, 256, 0, stream>>>(
                fh, fl, whp, wlp, inv, zpage, slab, slab_elems, l.nout, kpb); break;
        case 11:
            mconv_kernel<64, 128, 3, 3, false><<<grid, 256, 0, stream>>>(
                fh, fl, whp, wlp, inv, zpage, slab, slab_elems, l.nout, kpb); break;
        default:
            mconv_kernel<64, 64, 27, 27, false><<<grid, 256, 0, stream>>>(
                fh, fl, whp, wlp, inv, zpage, slab, slab_elems, l.nout, kpb); break;
        }

        long total = (long)l.nout * l.co;
        unsigned rblocks = (unsigned)((total + TPB - 1) / TPB);
        const float* bn = (const float*)d_in[2 * l.wi + 1];
        if (i < 11) {
            reduce_bnrelu_kernel<true><<<dim3(rblocks), dim3(TPB), 0, stream>>>(
                slab, slab_elems, ys, bn, l.co,
                nullptr, ph[cset ^ 1], pl[cset ^ 1], total);
            cset ^= 1;
        } else {
            reduce_bnrelu_kernel<false><<<dim3(rblocks), dim3(TPB), 0, stream>>>(
                slab, slab_elems, ys, bn, l.co, bufA, nullptr, nullptr, total);
        }
    }

    // ---- segment max
    hipMemsetAsync(d_out, 0, (size_t)out_size * sizeof(float), stream);
    const int* bidx = (const int*)d_in[42];
    int nb = out_size / 128;
    segmax_kernel<<<dim3(128), dim3(256), 0, stream>>>(bufA, bidx, (float*)d_out, n5, nb);
}